// Round 2
// baseline (841.299 us; speedup 1.0000x reference)
//
#include <hip/hip_runtime.h>

// Attention fwd with exact-JAX dropout:
//   O = dropout_{p=0.1, key=42}( softmax(Q K^T / 0.1) ) @ V,  V == K (x2)
// Shapes: Q,K: [2,16,2048,64] f32.
// Round 2: fix RNG to jax_threefry_partitionable=True semantics:
//   bits(i) = o0 ^ o1, (o0,o1) = threefry2x32(key=(0,42), ctr=(hi=0, lo=i)),
//   i = C-order flat index into [2,16,2048,2048]; keep iff (bits>>9) < 7549747.

constexpr int S   = 2048;
constexpr int Dh  = 64;
constexpr int TQ  = 32;   // query rows per block
constexpr int TK  = 64;   // key rows per tile
constexpr unsigned KEEP_THR = 7549747u;    // (bits>>9) < THR  <=>  uniform < f32(0.9)
constexpr float ZS = 14.426950408889634f;  // 10 * log2(e): logits in log2 domain

// threefry2x32, 20 rounds, key = (0, 42); ks2 = 0 ^ 42 ^ 0x1BD11BDA = 0x1BD11BF0
__device__ __forceinline__ void threefry2x32(unsigned c0, unsigned c1,
                                             unsigned& o0, unsigned& o1) {
  unsigned x0 = c0;        // + ks0 (=0)
  unsigned x1 = c1 + 42u;  // + ks1
#define TFR(R) x0 += x1; x1 = (x1 << R) | (x1 >> (32 - R)); x1 ^= x0;
  TFR(13) TFR(15) TFR(26) TFR(6)
  x0 += 42u;          x1 += 0x1BD11BF1u;   // ks1 , ks2+1
  TFR(17) TFR(29) TFR(16) TFR(24)
  x0 += 0x1BD11BF0u;  x1 += 2u;            // ks2 , ks0+2
  TFR(13) TFR(15) TFR(26) TFR(6)
  /* ks0 = 0 */       x1 += 45u;           // ks0 , ks1+3
  TFR(17) TFR(29) TFR(16) TFR(24)
  x0 += 42u;          x1 += 0x1BD11BF4u;   // ks1 , ks2+4
  TFR(13) TFR(15) TFR(26) TFR(6)
  x0 += 0x1BD11BF0u;  x1 += 5u;            // ks2 , ks0+5
#undef TFR
  o0 = x0; o1 = x1;
}

__device__ __forceinline__ float redmax16(float v) {
  v = fmaxf(v, __shfl_xor(v, 1));
  v = fmaxf(v, __shfl_xor(v, 2));
  v = fmaxf(v, __shfl_xor(v, 4));
  v = fmaxf(v, __shfl_xor(v, 8));
  return v;
}
__device__ __forceinline__ float redsum16(float v) {
  v += __shfl_xor(v, 1);
  v += __shfl_xor(v, 2);
  v += __shfl_xor(v, 4);
  v += __shfl_xor(v, 8);
  return v;
}

__global__ __launch_bounds__(256, 4) void attn_fwd(const float* __restrict__ Q,
                                                   const float* __restrict__ KV,
                                                   float* __restrict__ O) {
  __shared__ float Qs[TQ][Dh + 4];   // stride 68 floats
  __shared__ float Ks[TK][Dh + 4];   // K tile (doubles as V tile)
  __shared__ float Pt[TK][TQ + 4];   // masked probs, TRANSPOSED [t][r]

  const int tid = threadIdx.x;
  const int ty  = tid >> 4;          // 0..15
  const int tx  = tid & 15;          // 0..15
  const int bh  = blockIdx.y;        // 0..31  (= b*16 + h)
  const int s0  = blockIdx.x * TQ;

  const float* Qb = Q  + ((size_t)bh * S + s0) * Dh;
  const float* Kb = KV + (size_t)bh * S * Dh;

  // stage Q tile (32 rows x 64)
#pragma unroll
  for (int k = 0; k < TQ / 16; ++k) {
    const int r = ty + k * 16;
    *(float4*)&Qs[r][tx * 4] = *(const float4*)&Qb[r * Dh + tx * 4];
  }

  float mz[2]     = {-1e30f, -1e30f};  // running max (log2 domain)
  float lsum[2]   = {0.f, 0.f};        // running denom (includes dropped!)
  float acc[2][4] = {};                // O partial: rows ty*2+i, cols tx*4..+3

  // flat C-order index base for element (bh, s0+ty*2, t=0) in [32,2048,2048]
  const unsigned base = (unsigned)(bh * S + s0 + ty * 2) * (unsigned)S;

  for (int t0 = 0; t0 < S; t0 += TK) {
    __syncthreads();  // previous PV done (also covers Q staging on iter 0)
#pragma unroll
    for (int k = 0; k < TK / 16; ++k) {
      const int r = ty + k * 16;
      *(float4*)&Ks[r][tx * 4] = *(const float4*)&Kb[(t0 + r) * Dh + tx * 4];
    }
    __syncthreads();

    // ---- scores: z[i][j] = q[ty*2+i] . k[tx+16j] ----
    float z[2][4] = {};
#pragma unroll 4
    for (int d = 0; d < Dh; d += 4) {
      float4 q0 = *(const float4*)&Qs[ty * 2 + 0][d];
      float4 q1 = *(const float4*)&Qs[ty * 2 + 1][d];
#pragma unroll
      for (int j = 0; j < 4; ++j) {
        float4 kv = *(const float4*)&Ks[tx + 16 * j][d];
        z[0][j] += q0.x * kv.x + q0.y * kv.y + q0.z * kv.z + q0.w * kv.w;
        z[1][j] += q1.x * kv.x + q1.y * kv.y + q1.z * kv.z + q1.w * kv.w;
      }
    }

    // ---- online softmax (log2 domain) ----
    float tmax[2];
#pragma unroll
    for (int i = 0; i < 2; ++i) {
      float m = -1e30f;
#pragma unroll
      for (int j = 0; j < 4; ++j) { z[i][j] *= ZS; m = fmaxf(m, z[i][j]); }
      tmax[i] = redmax16(m);
    }
    float pr[2][4];
#pragma unroll
    for (int i = 0; i < 2; ++i) {
      const float mn = fmaxf(mz[i], tmax[i]);
      const float sc = exp2f(mz[i] - mn);   // 0 on first tile
      mz[i] = mn;
      float rs = 0.f;
#pragma unroll
      for (int j = 0; j < 4; ++j) {
        const float p = exp2f(z[i][j] - mn);
        pr[i][j] = p;
        rs += p;
      }
      rs = redsum16(rs);                    // denom over ALL keys (pre-dropout)
      lsum[i] = lsum[i] * sc + rs;
#pragma unroll
      for (int c = 0; c < 4; ++c) acc[i][c] *= sc;
    }

    // ---- dropout mask (partitionable threefry) + transpose P into LDS ----
#pragma unroll
    for (int i = 0; i < 2; ++i) {
      const unsigned cb = base + (unsigned)i * (unsigned)S + (unsigned)(t0 + tx);
#pragma unroll
      for (int j = 0; j < 4; ++j) {
        unsigned o0, o1;
        threefry2x32(0u, cb + 16u * j, o0, o1);
        const unsigned bits = o0 ^ o1;
        const float pm = ((bits >> 9) < KEEP_THR) ? pr[i][j] : 0.f;
        Pt[tx + 16 * j][ty * 2 + i] = pm;
      }
    }
    __syncthreads();

    // ---- PV: out rows ty*2+i, dims tx*4..+3;  V == K tile ----
#pragma unroll 8
    for (int t = 0; t < TK; ++t) {
      const float2 p2 = *(const float2*)&Pt[t][ty * 2];
      const float4 vv = *(const float4*)&Ks[t][tx * 4];
      acc[0][0] += p2.x * vv.x; acc[0][1] += p2.x * vv.y;
      acc[0][2] += p2.x * vv.z; acc[0][3] += p2.x * vv.w;
      acc[1][0] += p2.y * vv.x; acc[1][1] += p2.y * vv.y;
      acc[1][2] += p2.y * vv.z; acc[1][3] += p2.y * vv.w;
    }
  }

  // ---- epilogue: divide by (denominator * keep_prob) ----
#pragma unroll
  for (int i = 0; i < 2; ++i) {
    const float inv = 1.f / (lsum[i] * 0.9f);   // f32(0.9) == f32(1-DROP_P)
    float4 o;
    o.x = acc[i][0] * inv;
    o.y = acc[i][1] * inv;
    o.z = acc[i][2] * inv;
    o.w = acc[i][3] * inv;
    *(float4*)&O[((size_t)bh * S + s0 + ty * 2 + i) * Dh + tx * 4] = o;
  }
}

extern "C" void kernel_launch(void* const* d_in, const int* in_sizes, int n_in,
                              void* d_out, int out_size, void* d_ws, size_t ws_size,
                              hipStream_t stream) {
  const float* Q  = (const float*)d_in[0];
  const float* KV = (const float*)d_in[1];
  float* O = (float*)d_out;
  dim3 grid(S / TQ, 32);  // 64 s-tiles x (B*H)
  attn_fwd<<<grid, 256, 0, stream>>>(Q, KV, O);
}

// Round 4
// 411.390 us; speedup vs baseline: 2.0450x; 2.0450x over previous
//
#include <hip/hip_runtime.h>

// O = dropout_{p=0.1,key=42}( softmax(Q K^T / 0.1) ) @ V,  V == K. [2,16,2048,64] f32.
// Round 3 (resubmit; R3 never ran - GPU acquisition timeout). MFMA path.
// Swapped QK^T (scores = K·Q^T in C-layout, q = lane&15) so softmax is lane-local
// over t + xor16/32, and P^T feeds PV directly as B-operand (no LDS round-trip).
// QK^T in split-bf16 (hi/lo, 3 terms); PV with RNE-bf16 P and V. RNG unchanged
// (partitionable threefry, bits = o0^o1, keep iff (bits>>9) < 7549747).

constexpr int S  = 2048;
constexpr unsigned KEEP_THR = 7549747u;
constexpr float ZS = 14.426950408889634f;  // 10*log2(e)

typedef __attribute__((ext_vector_type(4))) float f32x4;
typedef __attribute__((ext_vector_type(8))) short s16x8;
typedef __attribute__((ext_vector_type(4))) short s16x4;

union S8 { unsigned short u[8]; s16x8 v; };
union A8 { s16x4 h[2]; s16x8 v; };

__device__ __forceinline__ void threefry2x32(unsigned c0, unsigned c1,
                                             unsigned& o0, unsigned& o1) {
  unsigned x0 = c0;
  unsigned x1 = c1 + 42u;
#define TFR(R) x0 += x1; x1 = (x1 << R) | (x1 >> (32 - R)); x1 ^= x0;
  TFR(13) TFR(15) TFR(26) TFR(6)
  x0 += 42u;          x1 += 0x1BD11BF1u;
  TFR(17) TFR(29) TFR(16) TFR(24)
  x0 += 0x1BD11BF0u;  x1 += 2u;
  TFR(13) TFR(15) TFR(26) TFR(6)
                      x1 += 45u;
  TFR(17) TFR(29) TFR(16) TFR(24)
  x0 += 42u;          x1 += 0x1BD11BF4u;
  TFR(13) TFR(15) TFR(26) TFR(6)
  x0 += 0x1BD11BF0u;  x1 += 5u;
#undef TFR
  o0 = x0; o1 = x1;
}

__device__ __forceinline__ unsigned short rne_bf16(float x) {
  unsigned u = __builtin_bit_cast(unsigned, x);
  return (unsigned short)((u + 0x7fffu + ((u >> 16) & 1u)) >> 16);
}
__device__ __forceinline__ void split_bf16(float x, unsigned short& h, unsigned short& l) {
  unsigned u = __builtin_bit_cast(unsigned, x);
  h = (unsigned short)(u >> 16);                       // trunc
  float hf = __builtin_bit_cast(float, u & 0xffff0000u);
  l = rne_bf16(x - hf);                                // exact residual, rne
}

#define MFMA(A, B, C) __builtin_amdgcn_mfma_f32_16x16x32_bf16((A), (B), (C), 0, 0, 0)

__global__ __launch_bounds__(256, 2) void attn_fwd(const float* __restrict__ Q,
                                                   const float* __restrict__ KV,
                                                   float* __restrict__ O) {
  // K tile (=V tile), 64 t x 64 d, bf16. Swizzle: stored col = col ^ ((row&7)<<3).
  __shared__ short Kt_hi[64][64];  // [t][d] hi (trunc)   - QK^T A-frags
  __shared__ short Kt_lo[64][64];  // [t][d] lo           - QK^T A-frags
  __shared__ short Kd_v [64][64];  // [d][t] rne          - PV   A-frags

  const int tid  = threadIdx.x;
  const int w    = tid >> 6;       // wave 0..3
  const int lane = tid & 63;
  const int g    = lane >> 4;      // 0..3
  const int c    = lane & 15;      // 0..15
  const int bh   = blockIdx.y;     // 0..31
  const int qb   = blockIdx.x * 128 + w * 32;

  const float* Kb = KV + (size_t)bh * S * 64;

  // ---- Q fragments (held in registers for the whole block) ----
  // B-frag for QK^T: lane (g,c): col q = qb+16Qt+c, k-slots d = 32ch + 8g + j.
  s16x8 qh[2][2], ql[2][2];
#pragma unroll
  for (int Qt = 0; Qt < 2; ++Qt) {
    const float* Qr = Q + ((size_t)bh * S + qb + 16 * Qt + c) * 64;
#pragma unroll
    for (int ch = 0; ch < 2; ++ch) {
      float4 f0 = *(const float4*)(Qr + 32 * ch + 8 * g);
      float4 f1 = *(const float4*)(Qr + 32 * ch + 8 * g + 4);
      float e[8] = {f0.x, f0.y, f0.z, f0.w, f1.x, f1.y, f1.z, f1.w};
      S8 uh, ul;
#pragma unroll
      for (int j = 0; j < 8; ++j) split_bf16(e[j], uh.u[j], ul.u[j]);
      qh[Qt][ch] = uh.v; ql[Qt][ch] = ul.v;
    }
  }

  f32x4 oacc[4][2];                 // O^T acc: [Dtile][Qt], rows d=16D+4g+r, col q
#pragma unroll
  for (int D = 0; D < 4; ++D)
#pragma unroll
    for (int Qt = 0; Qt < 2; ++Qt) oacc[D][Qt] = 0.f;
  float mz[2]   = {-1e30f, -1e30f}; // running max (scaled/log2 domain)
  float lsum[2] = {0.f, 0.f};       // denom incl. dropped keys

  const unsigned bhu = (unsigned)bh;

#pragma unroll 1
  for (int t0 = 0; t0 < S; t0 += 64) {
    // ---- stage K tile: global->reg (before barrier, overlaps prev compute) ----
    const int tt = tid >> 2;          // t row 0..63
    const int dq = tid & 3;           // quarter-row
    const float* Kr = Kb + (size_t)(t0 + tt) * 64 + dq * 16;
    float4 kv[4];
#pragma unroll
    for (int i = 0; i < 4; ++i) kv[i] = *(const float4*)(Kr + 4 * i);

    __syncthreads();                  // prev tile's compute done
#pragma unroll
    for (int i = 0; i < 4; ++i) {
      const int d0 = dq * 16 + i * 4;
      float e[4] = {kv[i].x, kv[i].y, kv[i].z, kv[i].w};
      S8 uh, ul;
      unsigned short vr[4];
#pragma unroll
      for (int j = 0; j < 4; ++j) {
        split_bf16(e[j], uh.u[j], ul.u[j]);
        vr[j] = rne_bf16(e[j]);
      }
      const int dS = d0 ^ ((tt & 7) << 3);
      *(s16x4*)&Kt_hi[tt][dS] = *(s16x4*)&uh.u[0];
      *(s16x4*)&Kt_lo[tt][dS] = *(s16x4*)&ul.u[0];
#pragma unroll
      for (int dd = 0; dd < 4; ++dd) {
        const int d = d0 + dd;
        Kd_v[d][tt ^ ((d & 7) << 3)] = (short)vr[dd];
      }
    }
    __syncthreads();

    // ---- QK^T: S^T[t,q] = sum_d K[t,d] Q[q,d], split bf16, 3 terms ----
    f32x4 Sc[4][2];
#pragma unroll
    for (int T = 0; T < 4; ++T) {
      const int t  = 16 * T + c;
      const int sw = (c & 7) << 3;    // (t&7) == (c&7)
      s16x8 ah0 = *(const s16x8*)&Kt_hi[t][(8 * g) ^ sw];
      s16x8 ah1 = *(const s16x8*)&Kt_hi[t][(32 + 8 * g) ^ sw];
      s16x8 al0 = *(const s16x8*)&Kt_lo[t][(8 * g) ^ sw];
      s16x8 al1 = *(const s16x8*)&Kt_lo[t][(32 + 8 * g) ^ sw];
#pragma unroll
      for (int Qt = 0; Qt < 2; ++Qt) {
        f32x4 a = 0.f;
        a = MFMA(ah0, qh[Qt][0], a);
        a = MFMA(ah1, qh[Qt][1], a);
        a = MFMA(ah0, ql[Qt][0], a);
        a = MFMA(ah1, ql[Qt][1], a);
        a = MFMA(al0, qh[Qt][0], a);
        a = MFMA(al1, qh[Qt][1], a);
        Sc[T][Qt] = a;
      }
    }

    // ---- online softmax (per q = col; lane-local over t, then xor16/32) ----
    s16x8 pbf[2][2];                  // P^T B-frags [Qt][Cchunk]
#pragma unroll
    for (int Qt = 0; Qt < 2; ++Qt) {
      float tm = -1e30f;
#pragma unroll
      for (int T = 0; T < 4; ++T)
#pragma unroll
        for (int r = 0; r < 4; ++r) tm = fmaxf(tm, Sc[T][Qt][r]);
      tm = fmaxf(tm, __shfl_xor(tm, 16));
      tm = fmaxf(tm, __shfl_xor(tm, 32));
      const float mn = fmaxf(mz[Qt], tm * ZS);
      const float sc = exp2f(mz[Qt] - mn);
      mz[Qt] = mn;
      float rs = 0.f;
#pragma unroll
      for (int T = 0; T < 4; ++T)
#pragma unroll
        for (int r = 0; r < 4; ++r) {
          const float p = exp2f(Sc[T][Qt][r] * ZS - mn);
          Sc[T][Qt][r] = p;
          rs += p;
        }
      rs += __shfl_xor(rs, 16);
      rs += __shfl_xor(rs, 32);
      lsum[Qt] = lsum[Qt] * sc + rs;
#pragma unroll
      for (int D = 0; D < 4; ++D)
#pragma unroll
        for (int r = 0; r < 4; ++r) oacc[D][Qt][r] *= sc;

      // ---- dropout mask (threefry) + pack P^T -> bf16 B-frags ----
      const unsigned qg = (unsigned)(qb + 16 * Qt + c);
      const unsigned fbase = (bhu * 2048u + qg) * 2048u + (unsigned)t0;
#pragma unroll
      for (int C = 0; C < 2; ++C) {
        S8 u;
#pragma unroll
        for (int jT = 0; jT < 2; ++jT) {
          const int T = 2 * C + jT;
#pragma unroll
          for (int r = 0; r < 4; ++r) {
            unsigned o0, o1;
            threefry2x32(0u, fbase + (unsigned)(16 * T + 4 * g + r), o0, o1);
            const bool keep = (((o0 ^ o1) >> 9) < KEEP_THR);
            u.u[jT * 4 + r] = keep ? rne_bf16(Sc[T][Qt][r]) : (unsigned short)0;
          }
        }
        pbf[Qt][C] = u.v;
      }
    }

    // ---- PV: O^T[d,q] += sum_t V[t,d] P^T[t,q]; k-slot t = 32C+16jT+4g+r ----
#pragma unroll
    for (int D = 0; D < 4; ++D) {
      const int d  = 16 * D + c;
      const int sw = (d & 7) << 3;
#pragma unroll
      for (int C = 0; C < 2; ++C) {
        A8 a;
        a.h[0] = *(const s16x4*)&Kd_v[d][(32 * C + 4 * g) ^ sw];
        a.h[1] = *(const s16x4*)&Kd_v[d][(32 * C + 16 + 4 * g) ^ sw];
        oacc[D][0] = MFMA(a.v, pbf[0][C], oacc[D][0]);
        oacc[D][1] = MFMA(a.v, pbf[1][C], oacc[D][1]);
      }
    }
  }

  // ---- epilogue ----
#pragma unroll
  for (int Qt = 0; Qt < 2; ++Qt) {
    const float inv = 1.f / (lsum[Qt] * 0.9f);
    float* Orow = O + ((size_t)bh * S + qb + 16 * Qt + c) * 64;
#pragma unroll
    for (int D = 0; D < 4; ++D) {
      float4 o;
      o.x = oacc[D][Qt][0] * inv;
      o.y = oacc[D][Qt][1] * inv;
      o.z = oacc[D][Qt][2] * inv;
      o.w = oacc[D][Qt][3] * inv;
      *(float4*)(Orow + 16 * D + 4 * g) = o;
    }
  }
}

extern "C" void kernel_launch(void* const* d_in, const int* in_sizes, int n_in,
                              void* d_out, int out_size, void* d_ws, size_t ws_size,
                              hipStream_t stream) {
  const float* Q  = (const float*)d_in[0];
  const float* KV = (const float*)d_in[1];
  float* O = (float*)d_out;
  dim3 grid(S / 128, 32);   // 16 q-blocks x 32 bh = 512 blocks (2/CU)
  attn_fwd<<<grid, 256, 0, stream>>>(Q, KV, O);
}

// Round 5
// 375.389 us; speedup vs baseline: 2.2411x; 1.0959x over previous
//
#include <hip/hip_runtime.h>

// O = dropout_{p=0.1,key=42}( softmax(Q K^T / 0.1) ) @ V,  V == K. [2,16,2048,64] f32.
// Round 5: occupancy + conversion-cost restructuring of the passing R4 design.
//  - 512-thread blocks (8 waves, 16 q-rows each), grid (16,32): 4 waves/SIMD.
//  - all f32->bf16 via v_cvt_pk_bf16_f32 (rne, packed) + v_perm packing;
//    split is hi = rne(x), lo = rne(x - hi); V tile = hi halves via v_perm.
//  - V tile writes: paired b32 along t, swizzle ((d&7)<<3)^((d>>3)<<2): conflict-free.
//  - threefry keep test folded to (o0^o1) < (THR<<9); rotates via rotateleft32.
//  - T13 defer-max: skip O/lsum rescale when no lane's max grew.

constexpr int S = 2048;
constexpr unsigned KEEP_HI = 3865470464u;   // 7549747u << 9
constexpr float ZS = 14.426950408889634f;   // 10*log2(e)

typedef __attribute__((ext_vector_type(4))) float f32x4;
typedef __attribute__((ext_vector_type(8))) short s16x8;
typedef __attribute__((ext_vector_type(4))) short s16x4;

union U8 { unsigned u32[4]; s16x8 v; };
union U4 { unsigned u32[2]; s16x4 v; };

__device__ __forceinline__ unsigned cvt_pk_bf16(float lo, float hi) {
  unsigned r;
  asm("v_cvt_pk_bf16_f32 %0, %1, %2" : "=v"(r) : "v"(lo), "v"(hi));
  return r;  // low16 = bf16(lo), high16 = bf16(hi), RNE
}
__device__ __forceinline__ float bflo(unsigned u) {  // expand low bf16 -> f32
  return __builtin_bit_cast(float, u << 16);
}
__device__ __forceinline__ float bfhi(unsigned u) {  // expand high bf16 -> f32
  return __builtin_bit_cast(float, u & 0xffff0000u);
}

__device__ __forceinline__ void threefry2x32(unsigned c0, unsigned c1,
                                             unsigned& o0, unsigned& o1) {
  unsigned x0 = c0;
  unsigned x1 = c1 + 42u;
#define TFR(R) x0 += x1; x1 = __builtin_rotateleft32(x1, R); x1 ^= x0;
  TFR(13) TFR(15) TFR(26) TFR(6)
  x0 += 42u;          x1 += 0x1BD11BF1u;
  TFR(17) TFR(29) TFR(16) TFR(24)
  x0 += 0x1BD11BF0u;  x1 += 2u;
  TFR(13) TFR(15) TFR(26) TFR(6)
                      x1 += 45u;
  TFR(17) TFR(29) TFR(16) TFR(24)
  x0 += 42u;          x1 += 0x1BD11BF4u;
  TFR(13) TFR(15) TFR(26) TFR(6)
  x0 += 0x1BD11BF0u;  x1 += 5u;
#undef TFR
  o0 = x0; o1 = x1;
}

#define MFMA(A, B, C) __builtin_amdgcn_mfma_f32_16x16x32_bf16((A), (B), (C), 0, 0, 0)

__global__ __launch_bounds__(512, 4) void attn_fwd(const float* __restrict__ Q,
                                                   const float* __restrict__ KV,
                                                   float* __restrict__ O) {
  // K tile (=V tile), 64 t x 64 d bf16. Kt_*: [t][d], col ^= (t&7)<<3.
  // Kv: [d][t] (V = rne(K) = hi), col ^= ((d&7)<<3) ^ ((d>>3)<<2).
  __shared__ short Kt_hi[64][64];
  __shared__ short Kt_lo[64][64];
  __shared__ short Kv[64][64];

  const int tid  = threadIdx.x;
  const int w    = tid >> 6;        // wave 0..7
  const int lane = tid & 63;
  const int g    = lane >> 4;       // 0..3
  const int c    = lane & 15;       // 0..15
  const int bh   = blockIdx.y;      // 0..31
  const int qw   = blockIdx.x * 128 + w * 16;   // wave's q-base (16 rows/wave)

  const float* Kb = KV + (size_t)bh * S * 64;

  // ---- Q fragments: row q = qw + c, k-slots d = 32ch + 8g + j ----
  s16x8 qh[2], ql[2];
  {
    const float* Qr = Q + ((size_t)bh * S + qw + c) * 64;
#pragma unroll
    for (int ch = 0; ch < 2; ++ch) {
      float4 f0 = *(const float4*)(Qr + 32 * ch + 8 * g);
      float4 f1 = *(const float4*)(Qr + 32 * ch + 8 * g + 4);
      float e[8] = {f0.x, f0.y, f0.z, f0.w, f1.x, f1.y, f1.z, f1.w};
      U8 H, L;
#pragma unroll
      for (int p = 0; p < 4; ++p) {
        unsigned hu = cvt_pk_bf16(e[2 * p], e[2 * p + 1]);
        H.u32[p] = hu;
        L.u32[p] = cvt_pk_bf16(e[2 * p] - bflo(hu), e[2 * p + 1] - bfhi(hu));
      }
      qh[ch] = H.v; ql[ch] = L.v;
    }
  }

  f32x4 oacc[4];                    // O^T acc: rows d = 16D+4g+r, col q = qw+c
#pragma unroll
  for (int D = 0; D < 4; ++D) oacc[D] = 0.f;
  float mz = -1e30f, lsum = 0.f;

  // staging: thread -> rows t in {2tb, 2tb+1}, cols d in 4db..4db+3
  const int tb = tid >> 4;          // 0..31
  const int db = tid & 15;          // 0..15
  const float* Kst = Kb + (size_t)(2 * tb) * 64 + 4 * db;
  const unsigned fqbase = ((unsigned)bh * 2048u + (unsigned)(qw + c)) * 2048u;

#pragma unroll 1
  for (int t0 = 0; t0 < S; t0 += 64) {
    // ---- global loads early (overlap prev tile's compute) ----
    const float* Kp = Kst + (size_t)t0 * 64;
    float4 r0 = *(const float4*)(Kp);
    float4 r1 = *(const float4*)(Kp + 64);

    __syncthreads();                // prev tile's LDS reads done

    // ---- convert + stage: hi/lo split (rne) + V (= hi) transposed ----
    {
      float e0[4] = {r0.x, r0.y, r0.z, r0.w};
      float e1[4] = {r1.x, r1.y, r1.z, r1.w};
      U4 H0, H1, L0, L1;
#pragma unroll
      for (int p = 0; p < 2; ++p) {
        unsigned h0 = cvt_pk_bf16(e0[2 * p], e0[2 * p + 1]);
        unsigned h1 = cvt_pk_bf16(e1[2 * p], e1[2 * p + 1]);
        H0.u32[p] = h0; H1.u32[p] = h1;
        L0.u32[p] = cvt_pk_bf16(e0[2 * p] - bflo(h0), e0[2 * p + 1] - bfhi(h0));
        L1.u32[p] = cvt_pk_bf16(e1[2 * p] - bflo(h1), e1[2 * p + 1] - bfhi(h1));
      }
      const int t0r = 2 * tb, t1r = 2 * tb + 1;
      const int c0 = (4 * db) ^ ((t0r & 7) << 3);
      const int c1 = (4 * db) ^ ((t1r & 7) << 3);
      *(s16x4*)&Kt_hi[t0r][c0] = H0.v;
      *(s16x4*)&Kt_hi[t1r][c1] = H1.v;
      *(s16x4*)&Kt_lo[t0r][c0] = L0.v;
      *(s16x4*)&Kt_lo[t1r][c1] = L1.v;
      // V words: [V(t0,d) | V(t1,d)<<16] via byte-perm of hi words
#pragma unroll
      for (int dd = 0; dd < 4; ++dd) {
        const unsigned sel = (dd & 1) ? 0x07060302u : 0x05040100u;
        const unsigned kvw = __builtin_amdgcn_perm(H1.u32[dd >> 1], H0.u32[dd >> 1], sel);
        const int d = 4 * db + dd;
        *(unsigned*)&Kv[d][(2 * tb) ^ (((d & 7) << 3) ^ ((d >> 3) << 2))] = kvw;
      }
    }
    __syncthreads();

    // ---- QK^T: S^T[t,q], split-bf16, 3 terms x 2 chunks ----
    f32x4 Sc[4];
#pragma unroll
    for (int T = 0; T < 4; ++T) {
      const int t  = 16 * T + c;
      const int sw = (c & 7) << 3;
      s16x8 ah0 = *(const s16x8*)&Kt_hi[t][(8 * g) ^ sw];
      s16x8 ah1 = *(const s16x8*)&Kt_hi[t][(32 + 8 * g) ^ sw];
      s16x8 al0 = *(const s16x8*)&Kt_lo[t][(8 * g) ^ sw];
      s16x8 al1 = *(const s16x8*)&Kt_lo[t][(32 + 8 * g) ^ sw];
      f32x4 a = 0.f;
      a = MFMA(ah0, qh[0], a);
      a = MFMA(ah1, qh[1], a);
      a = MFMA(ah0, ql[0], a);
      a = MFMA(ah1, ql[1], a);
      a = MFMA(al0, qh[0], a);
      a = MFMA(al1, qh[1], a);
      Sc[T] = a;
    }

    // ---- online softmax (per q-col; lane-local over t + xor16/32) ----
    float tm = -1e30f;
#pragma unroll
    for (int T = 0; T < 4; ++T)
#pragma unroll
      for (int r = 0; r < 4; ++r) tm = fmaxf(tm, Sc[T][r]);
    tm = fmaxf(tm, __shfl_xor(tm, 16));
    tm = fmaxf(tm, __shfl_xor(tm, 32));
    const float tms = tm * ZS;
    if (__any(tms > mz)) {          // T13: rescale only if some col's max grew
      const float mn = fmaxf(mz, tms);
      const float sc = exp2f(mz - mn);
      mz = mn;
      lsum *= sc;
#pragma unroll
      for (int D = 0; D < 4; ++D)
#pragma unroll
        for (int r = 0; r < 4; ++r) oacc[D][r] *= sc;
    }
    float rs = 0.f;
#pragma unroll
    for (int T = 0; T < 4; ++T)
#pragma unroll
      for (int r = 0; r < 4; ++r) {
        const float p = exp2f(fmaf(Sc[T][r], ZS, -mz));
        Sc[T][r] = p;
        rs += p;
      }
    rs += __shfl_xor(rs, 16);
    rs += __shfl_xor(rs, 32);
    lsum += rs;                     // denom over ALL keys (pre-dropout)

    // ---- dropout (partitionable threefry) + pack P^T -> bf16 B-frags ----
    s16x8 pbf[2];
    {
      const unsigned fb = fqbase + (unsigned)t0;
#pragma unroll
      for (int T = 0; T < 4; ++T)
#pragma unroll
        for (int r = 0; r < 4; ++r) {
          unsigned o0, o1;
          threefry2x32(0u, fb + (unsigned)(16 * T + 4 * g + r), o0, o1);
          if ((o0 ^ o1) >= KEEP_HI) Sc[T][r] = 0.f;
        }
#pragma unroll
      for (int C = 0; C < 2; ++C) {
        U8 u;
#pragma unroll
        for (int jT = 0; jT < 2; ++jT) {
          const int T = 2 * C + jT;
          u.u32[2 * jT + 0] = cvt_pk_bf16(Sc[T][0], Sc[T][1]);
          u.u32[2 * jT + 1] = cvt_pk_bf16(Sc[T][2], Sc[T][3]);
        }
        pbf[C] = u.v;
      }
    }

    // ---- PV: O^T[d,q] += V^T P^T; k-slot t = 32C + 16jT + 4g + r ----
#pragma unroll
    for (int D = 0; D < 4; ++D) {
      const int d  = 16 * D + c;
      const int sw = ((d & 7) << 3) ^ ((d >> 3) << 2);
#pragma unroll
      for (int C = 0; C < 2; ++C) {
        U8 a;
        *(s16x4*)&a.u32[0] = *(const s16x4*)&Kv[d][(32 * C + 4 * g) ^ sw];
        *(s16x4*)&a.u32[2] = *(const s16x4*)&Kv[d][(32 * C + 16 + 4 * g) ^ sw];
        oacc[D] = MFMA(a.v, pbf[C], oacc[D]);
      }
    }
  }

  // ---- epilogue: divide by (denominator * keep_prob) ----
  const float inv = 1.f / (lsum * 0.9f);
  float* Orow = O + ((size_t)bh * S + qw + c) * 64;
#pragma unroll
  for (int D = 0; D < 4; ++D) {
    float4 o;
    o.x = oacc[D][0] * inv;
    o.y = oacc[D][1] * inv;
    o.z = oacc[D][2] * inv;
    o.w = oacc[D][3] * inv;
    *(float4*)(Orow + 16 * D + 4 * g) = o;
  }
}

extern "C" void kernel_launch(void* const* d_in, const int* in_sizes, int n_in,
                              void* d_out, int out_size, void* d_ws, size_t ws_size,
                              hipStream_t stream) {
  const float* Q  = (const float*)d_in[0];
  const float* KV = (const float*)d_in[1];
  float* O = (float*)d_out;
  dim3 grid(S / 128, 32);   // 16 q-blocks x 32 bh = 512 blocks, 512 thr (2/CU)
  attn_fwd<<<grid, 512, 0, stream>>>(Q, KV, O);
}

// Round 6
// 311.333 us; speedup vs baseline: 2.7023x; 1.2057x over previous
//
#include <hip/hip_runtime.h>

// O = dropout_{p=0.1,key=42}( softmax(Q K^T / 0.1) ) @ V,  V == K. [2,16,2048,64] f32.
// Round 6 = R5 + sparsity-aware RNG/PV skipping:
//   softmax at scale 10 is near-one-hot; p underflows to 0 for ~99.5% of keys.
//   Mask on p==0 is a no-op and denom is pre-dropout, so threefry runs only for
//   slots where __any(p >= 1e-29) (wave-uniform branch), and PV chunks whose
//   32-key P block is all-zero skip pack + ds_reads + MFMAs. Error from the
//   threshold <= 2048*1e-29 — vastly below the 0.116 budget.

constexpr int S = 2048;
constexpr unsigned KEEP_HI = 3865470464u;   // 7549747u << 9
constexpr float ZS = 14.426950408889634f;   // 10*log2(e)
constexpr float PMIN = 1e-29f;              // numerator-relevance threshold

typedef __attribute__((ext_vector_type(4))) float f32x4;
typedef __attribute__((ext_vector_type(8))) short s16x8;
typedef __attribute__((ext_vector_type(4))) short s16x4;

union U8 { unsigned u32[4]; s16x8 v; };
union U4 { unsigned u32[2]; s16x4 v; };

__device__ __forceinline__ unsigned cvt_pk_bf16(float lo, float hi) {
  unsigned r;
  asm("v_cvt_pk_bf16_f32 %0, %1, %2" : "=v"(r) : "v"(lo), "v"(hi));
  return r;  // low16 = bf16(lo), high16 = bf16(hi), RNE
}
__device__ __forceinline__ float bflo(unsigned u) {
  return __builtin_bit_cast(float, u << 16);
}
__device__ __forceinline__ float bfhi(unsigned u) {
  return __builtin_bit_cast(float, u & 0xffff0000u);
}

__device__ __forceinline__ void threefry2x32(unsigned c0, unsigned c1,
                                             unsigned& o0, unsigned& o1) {
  unsigned x0 = c0;
  unsigned x1 = c1 + 42u;
#define TFR(R) x0 += x1; x1 = __builtin_rotateleft32(x1, R); x1 ^= x0;
  TFR(13) TFR(15) TFR(26) TFR(6)
  x0 += 42u;          x1 += 0x1BD11BF1u;
  TFR(17) TFR(29) TFR(16) TFR(24)
  x0 += 0x1BD11BF0u;  x1 += 2u;
  TFR(13) TFR(15) TFR(26) TFR(6)
                      x1 += 45u;
  TFR(17) TFR(29) TFR(16) TFR(24)
  x0 += 42u;          x1 += 0x1BD11BF4u;
  TFR(13) TFR(15) TFR(26) TFR(6)
  x0 += 0x1BD11BF0u;  x1 += 5u;
#undef TFR
  o0 = x0; o1 = x1;
}

#define MFMA(A, B, C) __builtin_amdgcn_mfma_f32_16x16x32_bf16((A), (B), (C), 0, 0, 0)

__global__ __launch_bounds__(512, 4) void attn_fwd(const float* __restrict__ Q,
                                                   const float* __restrict__ KV,
                                                   float* __restrict__ O) {
  // K tile (=V tile), 64 t x 64 d bf16. Kt_*: [t][d], col ^= (t&7)<<3.
  // Kv: [d][t] (V = rne(K) = hi), col ^= ((d&7)<<3) ^ ((d>>3)<<2).
  __shared__ short Kt_hi[64][64];
  __shared__ short Kt_lo[64][64];
  __shared__ short Kv[64][64];

  const int tid  = threadIdx.x;
  const int w    = tid >> 6;        // wave 0..7
  const int lane = tid & 63;
  const int g    = lane >> 4;       // 0..3
  const int c    = lane & 15;       // 0..15
  const int bh   = blockIdx.y;      // 0..31
  const int qw   = blockIdx.x * 128 + w * 16;   // wave's q-base

  const float* Kb = KV + (size_t)bh * S * 64;

  // ---- Q fragments: row q = qw + c, k-slots d = 32ch + 8g + j ----
  s16x8 qh[2], ql[2];
  {
    const float* Qr = Q + ((size_t)bh * S + qw + c) * 64;
#pragma unroll
    for (int ch = 0; ch < 2; ++ch) {
      float4 f0 = *(const float4*)(Qr + 32 * ch + 8 * g);
      float4 f1 = *(const float4*)(Qr + 32 * ch + 8 * g + 4);
      float e[8] = {f0.x, f0.y, f0.z, f0.w, f1.x, f1.y, f1.z, f1.w};
      U8 H, L;
#pragma unroll
      for (int p = 0; p < 4; ++p) {
        unsigned hu = cvt_pk_bf16(e[2 * p], e[2 * p + 1]);
        H.u32[p] = hu;
        L.u32[p] = cvt_pk_bf16(e[2 * p] - bflo(hu), e[2 * p + 1] - bfhi(hu));
      }
      qh[ch] = H.v; ql[ch] = L.v;
    }
  }

  f32x4 oacc[4];                    // O^T acc: rows d = 16D+4g+r, col q = qw+c
#pragma unroll
  for (int D = 0; D < 4; ++D) oacc[D] = 0.f;
  float mz = -1e30f, lsum = 0.f;

  const int tb = tid >> 4;          // 0..31
  const int db = tid & 15;          // 0..15
  const float* Kst = Kb + (size_t)(2 * tb) * 64 + 4 * db;
  const unsigned fqbase = ((unsigned)bh * 2048u + (unsigned)(qw + c)) * 2048u;

#pragma unroll 1
  for (int t0 = 0; t0 < S; t0 += 64) {
    // ---- global loads early (overlap prev tile's compute) ----
    const float* Kp = Kst + (size_t)t0 * 64;
    float4 r0 = *(const float4*)(Kp);
    float4 r1 = *(const float4*)(Kp + 64);

    __syncthreads();                // prev tile's LDS reads done

    // ---- convert + stage: hi/lo split (rne) + V (= hi) transposed ----
    {
      float e0[4] = {r0.x, r0.y, r0.z, r0.w};
      float e1[4] = {r1.x, r1.y, r1.z, r1.w};
      U4 H0, H1, L0, L1;
#pragma unroll
      for (int p = 0; p < 2; ++p) {
        unsigned h0 = cvt_pk_bf16(e0[2 * p], e0[2 * p + 1]);
        unsigned h1 = cvt_pk_bf16(e1[2 * p], e1[2 * p + 1]);
        H0.u32[p] = h0; H1.u32[p] = h1;
        L0.u32[p] = cvt_pk_bf16(e0[2 * p] - bflo(h0), e0[2 * p + 1] - bfhi(h0));
        L1.u32[p] = cvt_pk_bf16(e1[2 * p] - bflo(h1), e1[2 * p + 1] - bfhi(h1));
      }
      const int t0r = 2 * tb, t1r = 2 * tb + 1;
      const int c0 = (4 * db) ^ ((t0r & 7) << 3);
      const int c1 = (4 * db) ^ ((t1r & 7) << 3);
      *(s16x4*)&Kt_hi[t0r][c0] = H0.v;
      *(s16x4*)&Kt_hi[t1r][c1] = H1.v;
      *(s16x4*)&Kt_lo[t0r][c0] = L0.v;
      *(s16x4*)&Kt_lo[t1r][c1] = L1.v;
#pragma unroll
      for (int dd = 0; dd < 4; ++dd) {
        const unsigned sel = (dd & 1) ? 0x07060302u : 0x05040100u;
        const unsigned kvw = __builtin_amdgcn_perm(H1.u32[dd >> 1], H0.u32[dd >> 1], sel);
        const int d = 4 * db + dd;
        *(unsigned*)&Kv[d][(2 * tb) ^ (((d & 7) << 3) ^ ((d >> 3) << 2))] = kvw;
      }
    }
    __syncthreads();

    // ---- QK^T: S^T[t,q], split-bf16, 3 terms x 2 chunks ----
    f32x4 Sc[4];
#pragma unroll
    for (int T = 0; T < 4; ++T) {
      const int t  = 16 * T + c;
      const int sw = (c & 7) << 3;
      s16x8 ah0 = *(const s16x8*)&Kt_hi[t][(8 * g) ^ sw];
      s16x8 ah1 = *(const s16x8*)&Kt_hi[t][(32 + 8 * g) ^ sw];
      s16x8 al0 = *(const s16x8*)&Kt_lo[t][(8 * g) ^ sw];
      s16x8 al1 = *(const s16x8*)&Kt_lo[t][(32 + 8 * g) ^ sw];
      f32x4 a = 0.f;
      a = MFMA(ah0, qh[0], a);
      a = MFMA(ah1, qh[1], a);
      a = MFMA(ah0, ql[0], a);
      a = MFMA(ah1, ql[1], a);
      a = MFMA(al0, qh[0], a);
      a = MFMA(al1, qh[1], a);
      Sc[T] = a;
    }

    // ---- online softmax (per q-col; lane-local over t + xor16/32) ----
    float tm = -1e30f;
#pragma unroll
    for (int T = 0; T < 4; ++T)
#pragma unroll
      for (int r = 0; r < 4; ++r) tm = fmaxf(tm, Sc[T][r]);
    tm = fmaxf(tm, __shfl_xor(tm, 16));
    tm = fmaxf(tm, __shfl_xor(tm, 32));
    const float tms = tm * ZS;
    if (__any(tms > mz)) {
      const float mn = fmaxf(mz, tms);
      const float sc = exp2f(mz - mn);
      mz = mn;
      lsum *= sc;
#pragma unroll
      for (int D = 0; D < 4; ++D)
#pragma unroll
        for (int r = 0; r < 4; ++r) oacc[D][r] *= sc;
    }
    float rs = 0.f;
#pragma unroll
    for (int T = 0; T < 4; ++T)
#pragma unroll
      for (int r = 0; r < 4; ++r) {
        const float p = exp2f(fmaf(Sc[T][r], ZS, -mz));
        Sc[T][r] = p;
        rs += p;
      }
    rs += __shfl_xor(rs, 16);
    rs += __shfl_xor(rs, 32);
    lsum += rs;                     // denom over ALL keys (pre-dropout)

    // ---- dropout: threefry ONLY where some lane's p is numerically relevant ----
    bool cNZ[2] = {false, false};
    {
      const unsigned fb = fqbase + (unsigned)t0;
#pragma unroll
      for (int T = 0; T < 4; ++T)
#pragma unroll
        for (int r = 0; r < 4; ++r) {
          if (__any(Sc[T][r] >= PMIN)) {       // wave-uniform branch
            unsigned o0, o1;
            threefry2x32(0u, fb + (unsigned)(16 * T + 4 * g + r), o0, o1);
            if ((o0 ^ o1) >= KEEP_HI) Sc[T][r] = 0.f;
            cNZ[T >> 1] = true;
          } else {
            Sc[T][r] = 0.f;                    // mask irrelevant at this magnitude
          }
        }
    }

    // ---- PV only for chunks with any surviving mass ----
#pragma unroll
    for (int C = 0; C < 2; ++C) {
      if (!cNZ[C]) continue;                   // B-block all zero -> MFMA no-op
      U8 u;
#pragma unroll
      for (int jT = 0; jT < 2; ++jT) {
        const int T = 2 * C + jT;
        u.u32[2 * jT + 0] = cvt_pk_bf16(Sc[T][0], Sc[T][1]);
        u.u32[2 * jT + 1] = cvt_pk_bf16(Sc[T][2], Sc[T][3]);
      }
#pragma unroll
      for (int D = 0; D < 4; ++D) {
        const int d  = 16 * D + c;
        const int sw = ((d & 7) << 3) ^ ((d >> 3) << 2);
        U8 a;
        *(s16x4*)&a.u32[0] = *(const s16x4*)&Kv[d][(32 * C + 4 * g) ^ sw];
        *(s16x4*)&a.u32[2] = *(const s16x4*)&Kv[d][(32 * C + 16 + 4 * g) ^ sw];
        oacc[D] = MFMA(a.v, u.v, oacc[D]);
      }
    }
  }

  // ---- epilogue: divide by (denominator * keep_prob) ----
  const float inv = 1.f / (lsum * 0.9f);
  float* Orow = O + ((size_t)bh * S + qw + c) * 64;
#pragma unroll
  for (int D = 0; D < 4; ++D) {
    float4 o;
    o.x = oacc[D][0] * inv;
    o.y = oacc[D][1] * inv;
    o.z = oacc[D][2] * inv;
    o.w = oacc[D][3] * inv;
    *(float4*)(Orow + 16 * D + 4 * g) = o;
  }
}

extern "C" void kernel_launch(void* const* d_in, const int* in_sizes, int n_in,
                              void* d_out, int out_size, void* d_ws, size_t ws_size,
                              hipStream_t stream) {
  const float* Q  = (const float*)d_in[0];
  const float* KV = (const float*)d_in[1];
  float* O = (float*)d_out;
  dim3 grid(S / 128, 32);   // 16 q-blocks x 32 bh, 512 thr (2 blocks/CU)
  attn_fwd<<<grid, 512, 0, stream>>>(Q, KV, O);
}

// Round 11
// 192.735 us; speedup vs baseline: 4.3651x; 1.6153x over previous
//
#include <hip/hip_runtime.h>

// O = dropout_{p=0.1,key=42}( softmax(Q K^T / 0.1) ) @ V,  V == K. [2,16,2048,64] f32.
// Round 7 (5th submit; prior four hit GPU acquisition timeouts - never ran).
// = R6 + full-slot sparsity: near-one-hot softmax means only slots with
// z >= max-30 (log2) matter for BOTH numerator and (pre-dropout) denominator
// (lsum_final >= 1, so sub-2^-30 terms are < 1e-5 relative). One wave-uniform
// screen per 16-lane slot gates exp2+sum+threefry+PV. Native exp2 builtin.

constexpr int S = 2048;
constexpr unsigned KEEP_HI = 3865470464u;   // 7549747u << 9
constexpr float ZS = 14.426950408889634f;   // 10*log2(e)
constexpr float INV_ZS = 0.06931471805599453f;  // 1/ZS
constexpr float ZMARGIN = 30.0f;            // keep slots within 30 log2-units of max

typedef __attribute__((ext_vector_type(4))) float f32x4;
typedef __attribute__((ext_vector_type(8))) short s16x8;
typedef __attribute__((ext_vector_type(4))) short s16x4;

union U8 { unsigned u32[4]; s16x8 v; };
union U4 { unsigned u32[2]; s16x4 v; };

__device__ __forceinline__ unsigned cvt_pk_bf16(float lo, float hi) {
  unsigned r;
  asm("v_cvt_pk_bf16_f32 %0, %1, %2" : "=v"(r) : "v"(lo), "v"(hi));
  return r;  // low16 = bf16(lo), high16 = bf16(hi), RNE
}
__device__ __forceinline__ float bflo(unsigned u) {
  return __builtin_bit_cast(float, u << 16);
}
__device__ __forceinline__ float bfhi(unsigned u) {
  return __builtin_bit_cast(float, u & 0xffff0000u);
}

__device__ __forceinline__ void threefry2x32(unsigned c0, unsigned c1,
                                             unsigned& o0, unsigned& o1) {
  unsigned x0 = c0;
  unsigned x1 = c1 + 42u;
#define TFR(R) x0 += x1; x1 = __builtin_rotateleft32(x1, R); x1 ^= x0;
  TFR(13) TFR(15) TFR(26) TFR(6)
  x0 += 42u;          x1 += 0x1BD11BF1u;
  TFR(17) TFR(29) TFR(16) TFR(24)
  x0 += 0x1BD11BF0u;  x1 += 2u;
  TFR(13) TFR(15) TFR(26) TFR(6)
                      x1 += 45u;
  TFR(17) TFR(29) TFR(16) TFR(24)
  x0 += 42u;          x1 += 0x1BD11BF4u;
  TFR(13) TFR(15) TFR(26) TFR(6)
  x0 += 0x1BD11BF0u;  x1 += 5u;
#undef TFR
  o0 = x0; o1 = x1;
}

#define MFMA(A, B, C) __builtin_amdgcn_mfma_f32_16x16x32_bf16((A), (B), (C), 0, 0, 0)

__global__ __launch_bounds__(512, 4) void attn_fwd(const float* __restrict__ Q,
                                                   const float* __restrict__ KV,
                                                   float* __restrict__ O) {
  // K tile (=V tile), 64 t x 64 d bf16. Kt_*: [t][d], col ^= (t&7)<<3.
  // Kv: [d][t] (V = rne(K) = hi), col ^= ((d&7)<<3) ^ ((d>>3)<<2).
  __shared__ short Kt_hi[64][64];
  __shared__ short Kt_lo[64][64];
  __shared__ short Kv[64][64];

  const int tid  = threadIdx.x;
  const int w    = tid >> 6;        // wave 0..7
  const int lane = tid & 63;
  const int g    = lane >> 4;       // 0..3
  const int c    = lane & 15;       // 0..15
  const int bh   = blockIdx.y;      // 0..31
  const int qw   = blockIdx.x * 128 + w * 16;   // wave's q-base

  const float* Kb = KV + (size_t)bh * S * 64;

  // ---- Q fragments: row q = qw + c, k-slots d = 32ch + 8g + j ----
  s16x8 qh[2], ql[2];
  {
    const float* Qr = Q + ((size_t)bh * S + qw + c) * 64;
#pragma unroll
    for (int ch = 0; ch < 2; ++ch) {
      float4 f0 = *(const float4*)(Qr + 32 * ch + 8 * g);
      float4 f1 = *(const float4*)(Qr + 32 * ch + 8 * g + 4);
      float e[8] = {f0.x, f0.y, f0.z, f0.w, f1.x, f1.y, f1.z, f1.w};
      U8 H, L;
#pragma unroll
      for (int p = 0; p < 4; ++p) {
        unsigned hu = cvt_pk_bf16(e[2 * p], e[2 * p + 1]);
        H.u32[p] = hu;
        L.u32[p] = cvt_pk_bf16(e[2 * p] - bflo(hu), e[2 * p + 1] - bfhi(hu));
      }
      qh[ch] = H.v; ql[ch] = L.v;
    }
  }

  f32x4 oacc[4];                    // O^T acc: rows d = 16D+4g+r, col q = qw+c
#pragma unroll
  for (int D = 0; D < 4; ++D) oacc[D] = 0.f;
  float mz = -1e30f, lsum = 0.f;

  const int tb = tid >> 4;          // 0..31
  const int db = tid & 15;          // 0..15
  const float* Kst = Kb + (size_t)(2 * tb) * 64 + 4 * db;
  const unsigned fqbase = ((unsigned)bh * 2048u + (unsigned)(qw + c)) * 2048u;

#pragma unroll 1
  for (int t0 = 0; t0 < S; t0 += 64) {
    // ---- global loads early (overlap prev tile's compute) ----
    const float* Kp = Kst + (size_t)t0 * 64;
    float4 r0 = *(const float4*)(Kp);
    float4 r1 = *(const float4*)(Kp + 64);

    __syncthreads();                // prev tile's LDS reads done

    // ---- convert + stage: hi/lo split (rne) + V (= hi) transposed ----
    {
      float e0[4] = {r0.x, r0.y, r0.z, r0.w};
      float e1[4] = {r1.x, r1.y, r1.z, r1.w};
      U4 H0, H1, L0, L1;
#pragma unroll
      for (int p = 0; p < 2; ++p) {
        unsigned h0 = cvt_pk_bf16(e0[2 * p], e0[2 * p + 1]);
        unsigned h1 = cvt_pk_bf16(e1[2 * p], e1[2 * p + 1]);
        H0.u32[p] = h0; H1.u32[p] = h1;
        L0.u32[p] = cvt_pk_bf16(e0[2 * p] - bflo(h0), e0[2 * p + 1] - bfhi(h0));
        L1.u32[p] = cvt_pk_bf16(e1[2 * p] - bflo(h1), e1[2 * p + 1] - bfhi(h1));
      }
      const int t0r = 2 * tb, t1r = 2 * tb + 1;
      const int c0 = (4 * db) ^ ((t0r & 7) << 3);
      const int c1 = (4 * db) ^ ((t1r & 7) << 3);
      *(s16x4*)&Kt_hi[t0r][c0] = H0.v;
      *(s16x4*)&Kt_hi[t1r][c1] = H1.v;
      *(s16x4*)&Kt_lo[t0r][c0] = L0.v;
      *(s16x4*)&Kt_lo[t1r][c1] = L1.v;
#pragma unroll
      for (int dd = 0; dd < 4; ++dd) {
        const unsigned sel = (dd & 1) ? 0x07060302u : 0x05040100u;
        const unsigned kvw = __builtin_amdgcn_perm(H1.u32[dd >> 1], H0.u32[dd >> 1], sel);
        const int d = 4 * db + dd;
        *(unsigned*)&Kv[d][(2 * tb) ^ (((d & 7) << 3) ^ ((d >> 3) << 2))] = kvw;
      }
    }
    __syncthreads();

    // ---- QK^T: S^T[t,q], split-bf16, 3 terms x 2 chunks ----
    f32x4 Sc[4];
#pragma unroll
    for (int T = 0; T < 4; ++T) {
      const int t  = 16 * T + c;
      const int sw = (c & 7) << 3;
      s16x8 ah0 = *(const s16x8*)&Kt_hi[t][(8 * g) ^ sw];
      s16x8 ah1 = *(const s16x8*)&Kt_hi[t][(32 + 8 * g) ^ sw];
      s16x8 al0 = *(const s16x8*)&Kt_lo[t][(8 * g) ^ sw];
      s16x8 al1 = *(const s16x8*)&Kt_lo[t][(32 + 8 * g) ^ sw];
      f32x4 a = 0.f;
      a = MFMA(ah0, qh[0], a);
      a = MFMA(ah1, qh[1], a);
      a = MFMA(ah0, ql[0], a);
      a = MFMA(ah1, ql[1], a);
      a = MFMA(al0, qh[0], a);
      a = MFMA(al1, qh[1], a);
      Sc[T] = a;
    }

    // ---- tile max (per q-col; lane-local over t + xor16/32) ----
    float tm = -1e30f;
#pragma unroll
    for (int T = 0; T < 4; ++T)
#pragma unroll
      for (int r = 0; r < 4; ++r) tm = __builtin_fmaxf(tm, Sc[T][r]);
    tm = __builtin_fmaxf(tm, __shfl_xor(tm, 16));
    tm = __builtin_fmaxf(tm, __shfl_xor(tm, 32));
    const float tms = tm * ZS;
    if (__any(tms > mz)) {          // rescale only if some col's max grew
      const float mn = __builtin_fmaxf(mz, tms);
      const float sc = __builtin_amdgcn_exp2f(mz - mn);
      mz = mn;
      lsum *= sc;
#pragma unroll
      for (int D = 0; D < 4; ++D)
#pragma unroll
        for (int r = 0; r < 4; ++r) oacc[D][r] *= sc;
    }

    // ---- merged screen: slot relevant iff any lane has z >= mz - 30 (log2) ----
    // survivors: p = exp2(z*ZS - mz), add to denom, threefry dropout.
    // dead slots: p := 0 (denominator error < 2048*2^-30, output error ~1e-5).
    const float thr = (mz - ZMARGIN) * INV_ZS;   // raw-score threshold, per lane
    float rs = 0.f;
    bool cNZ[2] = {false, false};
    {
      const unsigned fb = fqbase + (unsigned)t0;
#pragma unroll
      for (int T = 0; T < 4; ++T)
#pragma unroll
        for (int r = 0; r < 4; ++r) {
          if (__any(Sc[T][r] >= thr)) {          // wave-uniform branch
            const float p = __builtin_amdgcn_exp2f(__builtin_fmaf(Sc[T][r], ZS, -mz));
            rs += p;
            unsigned o0, o1;
            threefry2x32(0u, fb + (unsigned)(16 * T + 4 * g + r), o0, o1);
            Sc[T][r] = ((o0 ^ o1) < KEEP_HI) ? p : 0.f;
            cNZ[T >> 1] = true;
          } else {
            Sc[T][r] = 0.f;
          }
        }
    }
    rs += __shfl_xor(rs, 16);
    rs += __shfl_xor(rs, 32);
    lsum += rs;                     // denom over all relevant keys (pre-dropout)

    // ---- PV only for chunks with any surviving mass ----
#pragma unroll
    for (int C = 0; C < 2; ++C) {
      if (!cNZ[C]) continue;                   // B-block all zero -> MFMA no-op
      U8 u;
#pragma unroll
      for (int jT = 0; jT < 2; ++jT) {
        const int T = 2 * C + jT;
        u.u32[2 * jT + 0] = cvt_pk_bf16(Sc[T][0], Sc[T][1]);
        u.u32[2 * jT + 1] = cvt_pk_bf16(Sc[T][2], Sc[T][3]);
      }
#pragma unroll
      for (int D = 0; D < 4; ++D) {
        const int d  = 16 * D + c;
        const int sw = ((d & 7) << 3) ^ ((d >> 3) << 2);
        U8 a;
        *(s16x4*)&a.u32[0] = *(const s16x4*)&Kv[d][(32 * C + 4 * g) ^ sw];
        *(s16x4*)&a.u32[2] = *(const s16x4*)&Kv[d][(32 * C + 16 + 4 * g) ^ sw];
        oacc[D] = MFMA(a.v, u.v, oacc[D]);
      }
    }
  }

  // ---- epilogue: divide by (denominator * keep_prob) ----
  const float inv = 1.f / (lsum * 0.9f);
  float* Orow = O + ((size_t)bh * S + qw + c) * 64;
#pragma unroll
  for (int D = 0; D < 4; ++D) {
    float4 o;
    o.x = oacc[D][0] * inv;
    o.y = oacc[D][1] * inv;
    o.z = oacc[D][2] * inv;
    o.w = oacc[D][3] * inv;
    *(float4*)(Orow + 16 * D + 4 * g) = o;
  }
}

extern "C" void kernel_launch(void* const* d_in, const int* in_sizes, int n_in,
                              void* d_out, int out_size, void* d_ws, size_t ws_size,
                              hipStream_t stream) {
  const float* Q  = (const float*)d_in[0];
  const float* KV = (const float*)d_in[1];
  float* O = (float*)d_out;
  dim3 grid(S / 128, 32);   // 16 q-blocks x 32 bh, 512 thr (2 blocks/CU)
  attn_fwd<<<grid, 512, 0, stream>>>(Q, KV, O);
}